// Round 2
// baseline (4305.830 us; speedup 1.0000x reference)
//
#include <hip/hip_runtime.h>
#include <stdint.h>

#define V_ITEMS 100000
#define EDIM    128
#define BATCH   4096
#define HLEN    50
#define TOPK    21
#define NKEEP   32      // candidate superset per batch (margin over 21)
#define BTILE   16      // batches per block in scoring kernel
#define TPB     512     // threads per block (8 waves)
#define CAP     416     // candidate buffer capacity per batch
#define TRIG    128     // compact when cnt exceeds this
#define IPT     8       // items per thread per iteration
#define ITERSTEP (TPB*IPT)   // 4096 items per block-iteration

// ---------------- key packing: max(key) == max(val), tie -> min(idx) --------
__device__ inline uint64_t packkey(float v, unsigned idx) {
    unsigned u = __float_as_uint(v);
    u = (u & 0x80000000u) ? ~u : (u | 0x80000000u);   // orderable float
    return ((uint64_t)u << 32) | (uint64_t)(0xFFFFFFFFu - idx);
}
__device__ inline float unpackval(uint64_t k) {
    unsigned uv = (unsigned)(k >> 32);
    uv = (uv & 0x80000000u) ? (uv ^ 0x80000000u) : ~uv;
    return __uint_as_float(uv);
}
__device__ inline uint64_t wred_max(uint64_t k) {
    #pragma unroll
    for (int off = 32; off; off >>= 1) {
        uint64_t o = (uint64_t)__shfl_xor((unsigned long long)k, off);
        if (o > k) k = o;
    }
    return k;
}

// wave-cooperative top-NKEEP over vals[0..n) (index = idxs[i] or slot i).
// lane r (r<NKEEP) gets winner r in (*winv,*wini); *thr32 (all lanes) = 32nd val.
// Destructive: marks selected slots' vals to -inf.
template<bool HASIDX>
__device__ inline void wave_topk(float* vals, const int* idxs, int n, int lane,
                                 float* winv, int* wini, float* thr32) {
    float myv = -INFINITY; int myi = -1; float t = -INFINITY;
    for (int r = 0; r < NKEEP; r++) {
        uint64_t best = 0;
        for (int i = lane; i < n; i += 64) {
            int id = HASIDX ? idxs[i] : i;
            uint64_t k = packkey(vals[i], (unsigned)id);
            if (k > best) best = k;
        }
        best = wred_max(best);
        unsigned widx = 0xFFFFFFFFu - (unsigned)(best & 0xFFFFFFFFull);
        for (int i = lane; i < n; i += 64) {          // remove winner
            int id = HASIDX ? idxs[i] : i;
            if ((unsigned)id == widx) vals[i] = -INFINITY;
        }
        if (lane == r) { myv = unpackval(best); myi = (int)widx; }
        if (r == NKEEP - 1) t = unpackval(best);
    }
    *winv = myv; *wini = myi; *thr32 = t;
}

// ---------------- K1: masked mean-pool queries (fp32) -----------------------
__global__ __launch_bounds__(EDIM) void query_kernel(
        const int* __restrict__ seq, const int* __restrict__ len,
        const float* __restrict__ emb, float* __restrict__ qout) {
    int b = blockIdx.x, d = threadIdx.x;
    int n = len[b];
    float s = 0.f;
    for (int l = 0; l < n; l++) {
        int it = seq[b * HLEN + l];
        s += emb[(size_t)it * EDIM + d];
    }
    float denom = (float)(n > 0 ? n : 1);
    qout[(size_t)b * EDIM + d] = s / denom;
}

// ---------------- K2: fp32 scoring sweep + fused top-32 selection -----------
// __launch_bounds__(512, 2): 2 waves/EU min -> 256-VGPR budget. Grid is
// 256 blocks = 1 block/CU anyway, so capping at 128 VGPRs (the 512-default)
// bought no occupancy and caused 500 MB/dispatch of scratch-spill traffic (R1).
__global__ __launch_bounds__(TPB, 2) void score_topk(
        const float* __restrict__ q, const float* __restrict__ emb,
        int* __restrict__ candOut) {
    __shared__ __align__(16) float qs[BTILE * EDIM];       // 8 KB
    __shared__ __align__(16) float cbuf[BTILE * CAP * 2];  // 53 KB: cv | ci
    __shared__ int   cnt[BTILE];
    __shared__ float thr[BTILE];
    float* cv  = cbuf;
    int*   ci  = (int*)(cbuf + BTILE * CAP);
    float* raw = cbuf;                                     // iter0 overlay

    const int tid  = threadIdx.x;
    const int lane = tid & 63;
    const int w    = tid >> 6;          // wave id 0..7; wave owns batches w, w+8
    const int b0   = blockIdx.x * BTILE;

    for (int i = tid; i < BTILE * EDIM; i += TPB) qs[i] = q[(size_t)b0 * EDIM + i];
    __syncthreads();
    const float4* qs4 = (const float4*)qs;

    // ---- iter0: items [0,TPB): raw scores to LDS, then per-wave top-32 ----
    {
        const float4* er = (const float4*)(emb + (size_t)tid * EDIM);
        float acc[BTILE];
        #pragma unroll
        for (int b = 0; b < BTILE; b++) acc[b] = 0.f;
        #pragma unroll 4
        for (int d4 = 0; d4 < EDIM / 4; d4++) {
            float4 e = er[d4];
            #pragma unroll
            for (int b = 0; b < BTILE; b++) {
                float4 qv = qs4[b * (EDIM / 4) + d4];
                acc[b] += e.x * qv.x + e.y * qv.y + e.z * qv.z + e.w * qv.w;
            }
        }
        #pragma unroll
        for (int b = 0; b < BTILE; b++) raw[b * TPB + tid] = acc[b];
    }
    __syncthreads();
    float wv[2]; int wi[2]; float t32[2];
    for (int p = 0; p < 2; p++) {
        int b = w + p * 8;
        wave_topk<false>(raw + b * TPB, nullptr, TPB, lane, &wv[p], &wi[p], &t32[p]);
    }
    __syncthreads();   // done reading raw (it overlays cv/ci)
    for (int p = 0; p < 2; p++) {
        int b = w + p * 8;
        if (lane < NKEEP) { cv[b * CAP + lane] = wv[p]; ci[b * CAP + lane] = wi[p]; }
        if (lane == 0)    { cnt[b] = NKEEP; thr[b] = t32[p]; }
    }

    // ---- main sweep: items [TPB, V), IPT per thread per iteration ----
    for (int base = TPB; base < V_ITEMS; base += ITERSTEP) {
        __syncthreads();                  // publish thr/cnt from prev compaction
        float tr[BTILE];
        #pragma unroll
        for (int b = 0; b < BTILE; b++) tr[b] = thr[b];

        int it[IPT]; const float4* er[IPT];
        #pragma unroll
        for (int k = 0; k < IPT; k++) {
            it[k] = base + tid + k * TPB;
            int cl = it[k] < V_ITEMS ? it[k] : (V_ITEMS - 1);
            er[k] = (const float4*)(emb + (size_t)cl * EDIM);
        }
        float acc[IPT][BTILE];
        #pragma unroll
        for (int k = 0; k < IPT; k++)
            #pragma unroll
            for (int b = 0; b < BTILE; b++) acc[k][b] = 0.f;

        #pragma unroll 2
        for (int d4 = 0; d4 < EDIM / 4; d4++) {
            float4 e[IPT];
            #pragma unroll
            for (int k = 0; k < IPT; k++) e[k] = er[k][d4];
            #pragma unroll
            for (int b = 0; b < BTILE; b++) {
                float4 qv = qs4[b * (EDIM / 4) + d4];   // wave-uniform broadcast
                #pragma unroll
                for (int k = 0; k < IPT; k++)
                    acc[k][b] += e[k].x * qv.x + e[k].y * qv.y
                               + e[k].z * qv.z + e[k].w * qv.w;
            }
        }
        #pragma unroll
        for (int k = 0; k < IPT; k++) {
            if (it[k] < V_ITEMS) {
                #pragma unroll
                for (int b = 0; b < BTILE; b++) {
                    float s = acc[k][b];
                    if (s > tr[b]) {
                        int pz = atomicAdd(&cnt[b], 1);
                        if (pz < CAP) { cv[b * CAP + pz] = s; ci[b * CAP + pz] = it[k]; }
                    }
                }
            }
        }
        __syncthreads();                  // inserts visible
        for (int p = 0; p < 2; p++) {     // per-wave compaction of owned batches
            int b = w + p * 8;
            int c = min(cnt[b], CAP);
            if (c > TRIG) {
                float cwv; int cwi; float ct;
                wave_topk<true>(cv + b * CAP, ci + b * CAP, c, lane, &cwv, &cwi, &ct);
                if (lane < NKEEP) { cv[b * CAP + lane] = cwv; ci[b * CAP + lane] = cwi; }
                if (lane == 0)    { cnt[b] = NKEEP; thr[b] = ct; }
            }
        }
    }

    // ---- final: top-32 per batch -> candidate indices to workspace ----
    __syncthreads();
    for (int p = 0; p < 2; p++) {
        int b = w + p * 8;
        int c = min(cnt[b], CAP);
        float fwv; int fwi; float ft;
        wave_topk<true>(cv + b * CAP, ci + b * CAP, c, lane, &fwv, &fwi, &ft);
        if (lane < NKEEP) candOut[(size_t)(b0 + b) * NKEEP + lane] = fwi;
    }
}

// ---------------- K3: fp64 rescore of 32 candidates, emit exact top-21 ------
__global__ __launch_bounds__(64) void rescore(
        const int* __restrict__ seq, const int* __restrict__ len,
        const float* __restrict__ emb, const int* __restrict__ cand,
        float* __restrict__ out) {
    __shared__ double qd[EDIM];
    int b = blockIdx.x, lane = threadIdx.x;
    int n = len[b];
    double s0 = 0.0, s1 = 0.0;
    for (int l = 0; l < n; l++) {
        int itv = seq[b * HLEN + l];
        const float* e = emb + (size_t)itv * EDIM;
        s0 += (double)e[lane];
        s1 += (double)e[lane + 64];
    }
    double denom = (double)(n > 0 ? n : 1);
    qd[lane]      = s0 / denom;
    qd[lane + 64] = s1 / denom;
    __syncthreads();

    int c    = lane & 31;
    int half = lane >> 5;
    int idx  = cand[(size_t)b * NKEEP + c];
    const float* ev = emb + (size_t)idx * EDIM;
    double part = 0.0;
    int off = half * 64;
    for (int j = 0; j < 64; j++) part += qd[off + j] * (double)ev[off + j];
    part += __shfl_xor(part, 32);       // combine the two halves
    double val = part;

    if (lane < 32) {
        int rank = 0;
        for (int j = 0; j < 32; j++) {
            double vj = __shfl(val, j);
            int    ij = __shfl(idx, j);
            if (vj > val || (vj == val && ij < idx)) rank++;
        }
        if (rank < TOPK) {
            out[(size_t)b * TOPK + rank] = (float)val;                       // values
            out[(size_t)BATCH * TOPK + (size_t)b * TOPK + rank] = (float)idx; // indices
        }
    }
}

extern "C" void kernel_launch(void* const* d_in, const int* in_sizes, int n_in,
                              void* d_out, int out_size, void* d_ws, size_t ws_size,
                              hipStream_t stream) {
    const int*   seq = (const int*)d_in[0];
    const int*   len = (const int*)d_in[1];
    const float* emb = (const float*)d_in[2];
    float* out = (float*)d_out;

    float* qws  = (float*)d_ws;                                        // 2 MB
    int*   cand = (int*)((char*)d_ws + (size_t)BATCH * EDIM * sizeof(float)); // 512 KB

    query_kernel<<<BATCH, EDIM, 0, stream>>>(seq, len, emb, qws);
    score_topk<<<BATCH / BTILE, TPB, 0, stream>>>(qws, emb, cand);
    rescore<<<BATCH, 64, 0, stream>>>(seq, len, emb, cand, out);
}

// Round 3
// 589.325 us; speedup vs baseline: 7.3064x; 7.3064x over previous
//
#include <hip/hip_runtime.h>
#include <stdint.h>

#define V_ITEMS 100000
#define EDIM    128
#define BATCH   4096
#define HLEN    50
#define TOPK    21

#define MT      32            // batches per block in K2
#define VSPLIT  2
#define VRANGE  (V_ITEMS / VSPLIT)     // 50000
#define NCHUNK  (VRANGE / 16)          // 3125 16-item chunks per range
#define NITER   ((NCHUNK + 7) / 8)     // 391 iterations (8 waves)
#define CAP2    256           // per-batch candidate capacity
#define NKEEP   32            // superset kept per (batch, range)
#define NCAND   (NKEEP * VSPLIT)       // 64 candidates per batch into K3

typedef __attribute__((ext_vector_type(8))) short          bf16x8;
typedef __attribute__((ext_vector_type(4))) float          f32x4;
typedef __attribute__((ext_vector_type(8))) unsigned short u16x8;

__device__ inline unsigned short f2bf(float x) {           // RNE fp32->bf16
    unsigned u = __float_as_uint(x);
    return (unsigned short)((u + 0x7FFFu + ((u >> 16) & 1u)) >> 16);
}

// ---------------- K0: emb fp32 -> bf16 table in ws --------------------------
__global__ __launch_bounds__(256) void conv_bf16(
        const float* __restrict__ s, unsigned short* __restrict__ d) {
    size_t i = (size_t)blockIdx.x * 256 + threadIdx.x;     // 8 floats/thread
    const float4* sp = (const float4*)s + i * 2;
    float4 a = sp[0], b = sp[1];
    u16x8 o;
    o[0] = f2bf(a.x); o[1] = f2bf(a.y); o[2] = f2bf(a.z); o[3] = f2bf(a.w);
    o[4] = f2bf(b.x); o[5] = f2bf(b.y); o[6] = f2bf(b.z); o[7] = f2bf(b.w);
    *((u16x8*)d + i) = o;
}

// ---------------- K1: masked mean-pool queries -> bf16 ----------------------
__global__ __launch_bounds__(EDIM) void query_bf16(
        const int* __restrict__ seq, const int* __restrict__ len,
        const float* __restrict__ emb, unsigned short* __restrict__ qbf) {
    int b = blockIdx.x, d = threadIdx.x;
    int n = len[b];
    float s = 0.f;
    for (int l = 0; l < n; l++)
        s += emb[(size_t)seq[b * HLEN + l] * EDIM + d];
    qbf[b * EDIM + d] = f2bf(s / (float)(n > 0 ? n : 1));
}

// ---- exact top-32 of a batch's candidate buffer: ballot-bisection on keys --
__device__ inline void compact_batch(float* cv, int* ci, int* cnt, float* thr,
                                     int b, int lane) {
    int n = min(cnt[b], CAP2);
    float val[4]; int idx[4]; unsigned key[4];
    #pragma unroll
    for (int e = 0; e < 4; e++) {
        int i = lane + e * 64;
        if (i < n) {
            float v = cv[b * CAP2 + i];
            unsigned u = __float_as_uint(v);
            key[e] = (u & 0x80000000u) ? ~u : (u | 0x80000000u);
            val[e] = v; idx[e] = ci[b * CAP2 + i];
        } else { key[e] = 0u; val[e] = 0.f; idx[e] = 0; }
    }
    unsigned cur = 0u;                 // max T with count(key >= T) >= 32
    #pragma unroll 1
    for (int bit = 31; bit >= 0; bit--) {
        unsigned mid = cur | (1u << bit);
        int c = 0;
        #pragma unroll
        for (int e = 0; e < 4; e++)
            c += __popcll(__ballot(key[e] >= mid));
        if (c >= 32) cur = mid;
    }
    int base = 0;                      // ballot prefix-sum compaction, no atomics
    #pragma unroll
    for (int e = 0; e < 4; e++) {
        bool keep = key[e] >= cur;
        unsigned long long m = __ballot(keep);
        int p = base + (int)__popcll(m & ((1ull << lane) - 1ull));
        if (keep && p < NKEEP) { cv[b * CAP2 + p] = val[e]; ci[b * CAP2 + p] = idx[e]; }
        base += (int)__popcll(m);
    }
    if (lane == 0) {
        cnt[b] = NKEEP;
        thr[b] = (cur & 0x80000000u) ? __uint_as_float(cur ^ 0x80000000u)
                                     : __uint_as_float(~cur);
    }
}

// ---------------- K2: bf16-MFMA scoring + fused per-range top-32 ------------
// grid = 128 batch-groups x 2 V-halves. 8 waves/block sweep disjoint item
// chunks of the block's half; a-frags (32 batches x K=128) resident in VGPRs.
// Register budget kept < 128 (R2 post-mortem: allocator pins 128 and spills).
__global__ __launch_bounds__(512) void score_topk(
        const unsigned short* __restrict__ qbf,
        const unsigned short* __restrict__ ebf,
        int* __restrict__ candOut) {
    __shared__ float cv[MT * CAP2];    // 32 KB
    __shared__ int   ci[MT * CAP2];    // 32 KB
    __shared__ int   cnt[MT];
    __shared__ float thr[MT];

    const int tid  = threadIdx.x;
    const int lane = tid & 63;
    const int w    = tid >> 6;                       // wave 0..7
    const int mg   = blockIdx.x >> 1;
    const int vhalf = blockIdx.x & 1;
    const int b0   = mg * MT;
    const int n15  = lane & 15, quad = lane >> 4;

    if (tid < MT) { cnt[tid] = 0; thr[tid] = -INFINITY; }
    __syncthreads();

    // resident A-fragments: 2 msubs x 4 K-steps (32 VGPRs)
    bf16x8 afr[2][4];
    #pragma unroll
    for (int ms = 0; ms < 2; ms++)
        #pragma unroll
        for (int t = 0; t < 4; t++)
            afr[ms][t] = *(const bf16x8*)(qbf + (b0 + ms * 16 + n15) * EDIM
                                          + t * 32 + quad * 8);
    float thrR[8];
    #pragma unroll
    for (int i = 0; i < 8; i++) thrR[i] = -INFINITY;

    int nextEvt = 1;
    const int cbase0 = vhalf * NCHUNK;

    for (int iter = 0; iter < NITER; iter++) {
        int chunk = iter * 8 + w;
        bool act  = chunk < NCHUNK;
        int  cc   = act ? chunk : (NCHUNK - 1);      // clamp addresses, gate inserts
        int  cb   = cbase0 + cc;

        const unsigned short* bp = ebf + (cb * 16 + n15) * EDIM + quad * 8;
        bf16x8 bfr[4];
        #pragma unroll
        for (int t = 0; t < 4; t++) bfr[t] = *(const bf16x8*)(bp + t * 32);

        f32x4 acc0 = {0.f, 0.f, 0.f, 0.f}, acc1 = {0.f, 0.f, 0.f, 0.f};
        #pragma unroll
        for (int t = 0; t < 4; t++) {
            acc0 = __builtin_amdgcn_mfma_f32_16x16x32_bf16(afr[0][t], bfr[t], acc0, 0, 0, 0);
            acc1 = __builtin_amdgcn_mfma_f32_16x16x32_bf16(afr[1][t], bfr[t], acc1, 0, 0, 0);
        }
        // C/D: item n = lane&15 (col), batch row = quad*4 + reg  [m89/m91]
        if (act) {
            int item = cb * 16 + n15;
            #pragma unroll
            for (int ms = 0; ms < 2; ms++)
                #pragma unroll
                for (int r = 0; r < 4; r++) {
                    float s = ms ? acc1[r] : acc0[r];
                    if (s > thrR[ms * 4 + r]) {
                        int row = ms * 16 + (quad << 2) + r;
                        int pz = atomicAdd(&cnt[row], 1);
                        if (pz < CAP2) { cv[row * CAP2 + pz] = s; ci[row * CAP2 + pz] = item; }
                    }
                }
        }
        // static compaction schedule: iters 1,2,4,...,256, and the final iter.
        // Uniform across waves -> barrier counts always match.
        if (iter + 1 == nextEvt || iter + 1 == NITER) {
            if (iter + 1 == nextEvt) nextEvt <<= 1;
            bool fin = (iter + 1 == NITER);
            __syncthreads();
            #pragma unroll 1
            for (int j = 0; j < 4; j++) {
                int b = (w << 2) + j;
                if (fin || cnt[b] > 96) compact_batch(cv, ci, cnt, thr, b, lane);
            }
            __syncthreads();
            #pragma unroll
            for (int ms = 0; ms < 2; ms++)
                #pragma unroll
                for (int r = 0; r < 4; r++)
                    thrR[ms * 4 + r] = thr[ms * 16 + (quad << 2) + r];
        }
    }
    // final compact guaranteed cnt==32 per batch; emit candidate indices
    for (int j = 0; j < 4; j++) {
        int b = (w << 2) + j;
        if (lane < NKEEP)
            candOut[(b0 + b) * NCAND + vhalf * NKEEP + lane] = ci[b * CAP2 + lane];
    }
}

// ---------------- K3: fp64 rescore of 64 candidates, exact top-21 -----------
__global__ __launch_bounds__(128) void rescore(
        const int* __restrict__ seq, const int* __restrict__ len,
        const float* __restrict__ emb, const int* __restrict__ cand,
        float* __restrict__ out) {
    __shared__ double qd[EDIM];
    __shared__ double sv[NCAND];
    __shared__ int    si[NCAND];
    int b = blockIdx.x, t = threadIdx.x;
    int n = len[b];
    double s = 0.0;
    for (int l = 0; l < n; l++)
        s += (double)emb[(size_t)seq[b * HLEN + l] * EDIM + t];
    qd[t] = s / (double)(n > 0 ? n : 1);
    __syncthreads();

    int c = t >> 1, h = t & 1;                       // 2 threads per candidate
    int idx = cand[b * NCAND + c];
    const float4* ev = (const float4*)(emb + (size_t)idx * EDIM + h * 64);
    double part = 0.0;
    #pragma unroll 4
    for (int j = 0; j < 16; j++) {
        float4 e = ev[j];
        int d = h * 64 + j * 4;
        part += qd[d] * (double)e.x + qd[d + 1] * (double)e.y
              + qd[d + 2] * (double)e.z + qd[d + 3] * (double)e.w;
    }
    part += __shfl_xor(part, 1);                     // combine halves
    if (h == 0) { sv[c] = part; si[c] = idx; }
    __syncthreads();

    if (t < NCAND) {                                 // rank among 64 (ties: low idx)
        double v = sv[t]; int id = si[t];
        int rank = 0;
        for (int j = 0; j < NCAND; j++) {
            double vj = sv[j]; int ij = si[j];
            rank += (vj > v || (vj == v && ij < id)) ? 1 : 0;
        }
        if (rank < TOPK) {
            out[(size_t)b * TOPK + rank] = (float)v;
            out[(size_t)BATCH * TOPK + (size_t)b * TOPK + rank] = (float)id;
        }
    }
}

extern "C" void kernel_launch(void* const* d_in, const int* in_sizes, int n_in,
                              void* d_out, int out_size, void* d_ws, size_t ws_size,
                              hipStream_t stream) {
    const int*   seq = (const int*)d_in[0];
    const int*   len = (const int*)d_in[1];
    const float* emb = (const float*)d_in[2];
    float* out = (float*)d_out;

    // ws layout: q_bf [4096*128 u16] | emb_bf [100000*128 u16] | cand [4096*64 i32]
    unsigned short* qbf  = (unsigned short*)d_ws;
    unsigned short* ebf  = qbf + (size_t)BATCH * EDIM;
    int*            cand = (int*)(ebf + (size_t)V_ITEMS * EDIM);

    conv_bf16 <<<(V_ITEMS * EDIM) / (256 * 8), 256, 0, stream>>>(emb, ebf);
    query_bf16<<<BATCH, EDIM, 0, stream>>>(seq, len, emb, qbf);
    score_topk<<<(BATCH / MT) * VSPLIT, 512, 0, stream>>>(qbf, ebf, cand);
    rescore   <<<BATCH, EDIM, 0, stream>>>(seq, len, emb, cand, out);
}